// Round 1
// baseline (529.797 us; speedup 1.0000x reference)
//
#include <hip/hip_runtime.h>

// SSIM (B=16, C=3, H=W=512, fp32) -> scalar mean.
// v10: occupancy-targeted restructure of v9.
//  - 2-row steps (was 4): LDS = 4 plane regions x 5248 B = 21 KB (was 42 KB).
//    LDS now admits 7 blocks/CU; __launch_bounds__(256,6) -> 6 blocks/CU
//    = 24 waves/CU. Grid 48x32 = 1536 blocks = exactly 6/CU: whole grid
//    co-resident, no tail.
//  - Cross-step prefetch: next step's 2 rows x 2 images issued at step top
//    into pend regs, consumed next iteration -> one full step of latency hiding.
//  - Step loop fully unrolled: ring shift + pend become register renaming.
//  - Swizzle P = E + (E>>2) kept; reads and writes are both lane-stride-2
//    elements now -> near-conflict-free (enumerated mod 16).
//  - Same fused 4-plane math (mu1, mu2, x^2+y^2, xy), packed v2f fp32,
//    rcp+Newton, single atomicAdd per block.

typedef float v2f __attribute__((ext_vector_type(2)));

#define IMG_H 512
#define IMG_W 512
#define N_IMG 48                    // B*C
#define WS 11
#define PAD 5
#define CHUNK 16                    // output rows per block
#define NCHUNK (IMG_H / CHUNK)      // 32
#define RING 12                     // rows held in registers
#define PLANE_B 5248                // bytes per plane region (max off 5232)
#define INV_NPX (1.0f / (48.0f * 512.0f * 512.0f))

// swizzled byte offset of element E (element = 8B v2f {row_even,row_odd})
__device__ __forceinline__ unsigned swz8(int E) {
    return (unsigned)((E + (E >> 2)) * 8);
}
__device__ __forceinline__ v2f vfma(v2f a, v2f b, v2f c) {
    return __builtin_elementwise_fma(a, b, c);
}

__global__ __launch_bounds__(256, 6) void ssim_partial_kernel(
    const float* __restrict__ img1,
    const float* __restrict__ img2,
    const float* __restrict__ window,
    float* __restrict__ out)
{
    __shared__ __align__(16) char lds[4 * PLANE_B];   // region = plane
    __shared__ float wred[4];

    const int tid = threadIdx.x;
    const int bc  = blockIdx.x;              // image*channel 0..47
    const int r0  = blockIdx.y * CHUNK;
    const int col = tid * 2;                 // this thread owns cols col,col+1

    // 1-D gaussian from window row 5: w2d[5][j] = g5*g[j], g5 = sqrt(w2d[5][5]).
    float g[WS];
    {
        const float g5  = sqrtf(window[5 * WS + 5]);
        const float inv = 1.0f / g5;
#pragma unroll
        for (int j = 0; j < WS; ++j) g[j] = window[5 * WS + j] * inv;
    }
    const float C1v = 0.01f * 0.01f;
    const float C2v = 0.03f * 0.03f;

    const float* __restrict__ p1 = img1 + (size_t)bc * (IMG_H * IMG_W);
    const float* __restrict__ p2 = img2 + (size_t)bc * (IMG_H * IMG_W);

    // step-invariant LDS byte offsets
    const unsigned woffA = swz8(col + 6);      // write col   (E = 2t+6)
    const unsigned woffB = swz8(col + 7);      // write col+1 (E = 2t+7)
    unsigned roff[12];                         // reads: E = col+1 .. col+12
#pragma unroll
    for (int m = 0; m < 12; ++m) roff[m] = swz8(col + 1 + m);

    // zero halo elements once: E in {0..5, 518..523} per region (48 stores)
    if (tid < 48) {
        const int pj = tid / 12, h = tid % 12;
        const int E  = (h < 6) ? h : (512 + h);
        *(v2f*)(lds + pj * PLANE_B + swz8(E)) = (v2f)(0.0f);
    }
    __syncthreads();

    // register ring: slot i holds row R-5+i (after the shift at step base R)
    v2f rx1[RING], rx2[RING];
#pragma unroll
    for (int i = 0; i < RING; ++i) { rx1[i] = (v2f)(0.0f); rx2[i] = (v2f)(0.0f); }

    // warm-up: slots 2..11 <- rows r0-5 .. r0+4
#pragma unroll
    for (int i = 0; i < 10; ++i) {
        const int rr = r0 - PAD + i;
        v2f u1 = (v2f)(0.0f), u2 = (v2f)(0.0f);
        if (rr >= 0 && rr < IMG_H) {               // uniform branch
            u1 = *(const v2f*)(p1 + rr * IMG_W + col);
            u2 = *(const v2f*)(p2 + rr * IMG_W + col);
        }
        rx1[2 + i] = u1; rx2[2 + i] = u2;
    }
    // prefetch rows r0+5, r0+6 (consumed at step 0)
    v2f pend1[2], pend2[2];
#pragma unroll
    for (int j = 0; j < 2; ++j) {
        const int rr = r0 + PAD + j;
        v2f u1 = (v2f)(0.0f), u2 = (v2f)(0.0f);
        if (rr < IMG_H) {
            u1 = *(const v2f*)(p1 + rr * IMG_W + col);
            u2 = *(const v2f*)(p2 + rr * IMG_W + col);
        }
        pend1[j] = u1; pend2[j] = u2;
    }

    float acc = 0.0f;

#pragma unroll
    for (int step = 0; step < CHUNK / 2; ++step) {
        const int R = r0 + step * 2;           // output rows R, R+1 this step

        // shift ring by 2 (pure renaming after full unroll)
#pragma unroll
        for (int i = 0; i < RING - 2; ++i) { rx1[i] = rx1[i + 2]; rx2[i] = rx2[i + 2]; }
        rx1[10] = pend1[0]; rx2[10] = pend2[0];
        rx1[11] = pend1[1]; rx2[11] = pend2[1];

        // issue NEXT step's loads now; consumed one full step later
        if (step + 1 < CHUNK / 2) {            // constant-folds per iteration
#pragma unroll
            for (int j = 0; j < 2; ++j) {
                const int rr = R + 7 + j;      // (R+2) + PAD + j
                v2f u1 = (v2f)(0.0f), u2 = (v2f)(0.0f);
                if (rr < IMG_H) {              // uniform branch
                    u1 = *(const v2f*)(p1 + rr * IMG_W + col);
                    u2 = *(const v2f*)(p2 + rr * IMG_W + col);
                }
                pend1[j] = u1; pend2[j] = u2;
            }
        }

        // vertical gaussian sums: 4 planes x 2 rows, packed over the col pair.
        // (X1*X1+X2*X2 and X1*X2 per slot are CSE'd across the 2 rows.)
        v2f va[4][2];
#pragma unroll
        for (int p = 0; p < 4; ++p)
#pragma unroll
            for (int k = 0; k < 2; ++k) va[p][k] = (v2f)(0.0f);
#pragma unroll
        for (int k = 0; k < 2; ++k) {
#pragma unroll
            for (int i = 0; i < WS; ++i) {
                const v2f w  = (v2f)(g[i]);
                const v2f X1 = rx1[i + k], X2 = rx2[i + k];
                va[0][k] = vfma(w, X1, va[0][k]);
                va[1][k] = vfma(w, X2, va[1][k]);
                va[2][k] = vfma(w, vfma(X1, X1, X2 * X2), va[2][k]);
                va[3][k] = vfma(w, X1 * X2, va[3][k]);
            }
        }
        // repack {col-packed rows} -> {row-pair packed cols} and store
#pragma unroll
        for (int p = 0; p < 4; ++p) {
            char* base = lds + p * PLANE_B;
            *(v2f*)(base + woffA) = (v2f){va[p][0].x, va[p][1].x};
            *(v2f*)(base + woffB) = (v2f){va[p][0].y, va[p][1].y};
        }
        __syncthreads();

        // horizontal conv + SSIM: 2 cols (col, col+1), row pair (R, R+1)
        v2f h[4][2];                           // [plane][d]
#pragma unroll
        for (int p = 0; p < 4; ++p) {
            const char* base = lds + p * PLANE_B;
            v2f r[12];
#pragma unroll
            for (int m = 0; m < 12; ++m) r[m] = *(const v2f*)(base + roff[m]);
#pragma unroll
            for (int d = 0; d < 2; ++d) {
                v2f s = (v2f)(0.0f);
#pragma unroll
                for (int i = 0; i < WS; ++i) s = vfma((v2f)(g[i]), r[d + i], s);
                h[p][d] = s;
            }
        }
#pragma unroll
        for (int d = 0; d < 2; ++d) {
            const v2f mu1 = h[0][d], mu2 = h[1][d];
            const v2f hs  = h[2][d], hp  = h[3][d];
            const v2f mu1s = mu1 * mu1;
            const v2f mu2s = mu2 * mu2;
            const v2f mu12 = mu1 * mu2;
            const v2f sgs  = hs - mu1s - mu2s;       // sigma1^2 + sigma2^2
            const v2f sg12 = hp - mu12;
            const v2f num  = (2.f * mu12 + (v2f)(C1v)) * (2.f * sg12 + (v2f)(C2v));
            const v2f den  = (mu1s + mu2s + (v2f)(C1v)) * (sgs + (v2f)(C2v));
            v2f r = {__builtin_amdgcn_rcpf(den.x), __builtin_amdgcn_rcpf(den.y)};
            r = r * vfma(-den, r, (v2f)(2.0f));      // Newton -> ~1 ulp
            acc = fmaf(num.x, r.x, acc);
            acc = fmaf(num.y, r.y, acc);
        }
        if (step + 1 < CHUNK / 2) __syncthreads();   // before LDS overwrite
    }

    // block reduction -> single atomic per block (pre-scaled by 1/Npx)
#pragma unroll
    for (int off = 32; off > 0; off >>= 1)
        acc += __shfl_down(acc, off);
    if ((tid & 63) == 0) wred[tid >> 6] = acc;
    __syncthreads();
    if (tid == 0) {
        const float s = (wred[0] + wred[1]) + (wred[2] + wred[3]);
        atomicAdd(out, s * INV_NPX);
    }
}

extern "C" void kernel_launch(void* const* d_in, const int* in_sizes, int n_in,
                              void* d_out, int out_size, void* d_ws, size_t ws_size,
                              hipStream_t stream) {
    const float* img1   = (const float*)d_in[0];
    const float* img2   = (const float*)d_in[1];
    const float* window = (const float*)d_in[2];
    float* out = (float*)d_out;

    hipMemsetAsync(out, 0, sizeof(float), stream);   // graph-capturable
    dim3 grid(N_IMG, NCHUNK);
    ssim_partial_kernel<<<grid, 256, 0, stream>>>(img1, img2, window, out);
}

// Round 3
// 196.106 us; speedup vs baseline: 2.7016x; 2.7016x over previous
//
#include <hip/hip_runtime.h>

// SSIM (B=16, C=3, H=W=512, fp32) -> scalar mean.
// v11b: identical to v11 (round-1 submission hit an infra failure, no verdict).
// Register-squeezed single-round design:
//  - LDS layout: 8 scalar plane-row regions (4 planes x 2 rows), 528 dwords
//    each (halo 6 left / 6 right). Scalar elements => window reads and v2f
//    writes are lane-stride-2-dword = 2-way bank aliasing = FREE (no swizzle,
//    no roff table). All reads share ONE vaddr + compile-time immediates.
//  - g[] hoisted to SGPRs via readfirstlane (wave-uniform).
//  - No pend prefetch; 24 waves/CU give TLP to hide the 4 loads/step.
//  - __launch_bounds__(256,6): 6 blocks/CU x grid 1536 = whole grid
//    co-resident in a single round (v9 ran 2 rounds at 3/CU).
//  - Vertical conv keeps v2f col-pair packing; split into plane-pairs
//    (mu1/mu2 then S/P) to cap accumulator liveness.
//  - Horizontal conv streams 7 x ds_read_b64 per plane-row, FMAs applied as
//    data arrives (no s[14] array), SSIM stays v2f-packed per row.

typedef float v2f __attribute__((ext_vector_type(2)));

#define IMG_H 512
#define IMG_W 512
#define N_IMG 48                    // B*C
#define WS 11
#define PAD 5
#define CHUNK 16                    // output rows per block
#define NCHUNK (IMG_H / CHUNK)      // 32
#define RING 12                     // rows held in registers
#define REG_DW 528                  // dwords per plane-row region (524 used)
#define REG_B (REG_DW * 4)          // 2112 bytes
#define NREG 8                      // 4 planes x 2 rows
#define INV_NPX (1.0f / (48.0f * 512.0f * 512.0f))

__device__ __forceinline__ v2f vfma(v2f a, v2f b, v2f c) {
    return __builtin_elementwise_fma(a, b, c);
}
__device__ __forceinline__ float uni(float x) {   // force wave-uniform -> SGPR
    return __int_as_float(__builtin_amdgcn_readfirstlane(__float_as_int(x)));
}

__global__ __launch_bounds__(256, 6) void ssim_partial_kernel(
    const float* __restrict__ img1,
    const float* __restrict__ img2,
    const float* __restrict__ window,
    float* __restrict__ out)
{
    __shared__ __align__(16) char lds[NREG * REG_B];   // 16896 B
    __shared__ float wred[4];

    const int tid = threadIdx.x;
    const int bc  = blockIdx.x;              // image*channel 0..47
    const int r0  = blockIdx.y * CHUNK;
    const int c0  = tid * 2;                 // thread owns cols c0, c0+1

    // 1-D gaussian from window row 5 (w2d[5][j] = g5*g[j]); hoist to SGPRs.
    float g[WS];
    {
        const float g5  = sqrtf(window[5 * WS + 5]);
        const float inv = 1.0f / g5;
#pragma unroll
        for (int j = 0; j < WS; ++j) g[j] = uni(window[5 * WS + j] * inv);
    }
    const float C1v = 0.01f * 0.01f;
    const float C2v = 0.03f * 0.03f;

    const float* __restrict__ p1 = img1 + (size_t)bc * (IMG_H * IMG_W);
    const float* __restrict__ p2 = img2 + (size_t)bc * (IMG_H * IMG_W);

    // zero halo: dword idx 0..5 (cols -6..-1) and 518..523 (cols 512..517)
    if (tid < 96) {
        const int rg = tid / 12, h = tid % 12;
        const int idx = (h < 6) ? h : (512 + h);
        *(float*)(lds + rg * REG_B + idx * 4) = 0.0f;
    }
    __syncthreads();

    // LDS addressing: dword index of global col c is c+6 within a region.
    char*       wb = lds + (c0 + 6) * 4;     // write base (8B aligned)
    const char* rb = lds + c0 * 4;           // read base: col c0-6 (8B aligned)

    // register ring: slot i holds row R-5+i at step base R
    v2f rx1[RING], rx2[RING];
#pragma unroll
    for (int i = 0; i < RING; ++i) { rx1[i] = (v2f)(0.0f); rx2[i] = (v2f)(0.0f); }

    // warm-up: slots 2..11 <- rows r0-5 .. r0+4
#pragma unroll
    for (int i = 0; i < 10; ++i) {
        const int rr = r0 - PAD + i;
        v2f u1 = (v2f)(0.0f), u2 = (v2f)(0.0f);
        if (rr >= 0 && rr < IMG_H) {               // uniform branch
            u1 = *(const v2f*)(p1 + rr * IMG_W + c0);
            u2 = *(const v2f*)(p2 + rr * IMG_W + c0);
        }
        rx1[2 + i] = u1; rx2[2 + i] = u2;
    }

    float acc = 0.0f;

#pragma unroll
    for (int step = 0; step < CHUNK / 2; ++step) {
        const int R = r0 + step * 2;           // output rows R, R+1

        // shift ring by 2 (renaming after full unroll)
#pragma unroll
        for (int i = 0; i < RING - 2; ++i) { rx1[i] = rx1[i + 2]; rx2[i] = rx2[i + 2]; }
        // load rows R+5, R+6 -> slots 10, 11  (rr >= 5 always)
#pragma unroll
        for (int j = 0; j < 2; ++j) {
            const int rr = R + PAD + j;
            v2f u1 = (v2f)(0.0f), u2 = (v2f)(0.0f);
            if (rr < IMG_H) {                  // uniform branch
                u1 = *(const v2f*)(p1 + rr * IMG_W + c0);
                u2 = *(const v2f*)(p2 + rr * IMG_W + c0);
            }
            rx1[10 + j] = u1; rx2[10 + j] = u2;
        }

        // ---- vertical pass A: mu1, mu2 (planes 0,1), rows k=0,1 ----
        {
            v2f a0[2] = {(v2f)(0.0f), (v2f)(0.0f)};
            v2f a1[2] = {(v2f)(0.0f), (v2f)(0.0f)};
#pragma unroll
            for (int k = 0; k < 2; ++k)
#pragma unroll
                for (int i = 0; i < WS; ++i) {
                    const v2f w = (v2f)(g[i]);
                    a0[k] = vfma(w, rx1[i + k], a0[k]);
                    a1[k] = vfma(w, rx2[i + k], a1[k]);
                }
#pragma unroll
            for (int k = 0; k < 2; ++k) {
                *(v2f*)(wb + (0 + k) * REG_B) = a0[k];   // plane0 row k
                *(v2f*)(wb + (2 + k) * REG_B) = a1[k];   // plane1 row k
            }
        }
        // ---- vertical pass B: S = x1^2+x2^2, P = x1*x2 (planes 2,3) ----
        {
            v2f b0[2] = {(v2f)(0.0f), (v2f)(0.0f)};
            v2f b1[2] = {(v2f)(0.0f), (v2f)(0.0f)};
#pragma unroll
            for (int u = 0; u < RING; ++u) {
                const v2f X1 = rx1[u], X2 = rx2[u];
                const v2f S = vfma(X1, X1, X2 * X2);
                const v2f P = X1 * X2;
                if (u <= 10) {                          // k=0 tap i=u
                    b0[0] = vfma((v2f)(g[u]), S, b0[0]);
                    b1[0] = vfma((v2f)(g[u]), P, b1[0]);
                }
                if (u >= 1) {                           // k=1 tap i=u-1
                    b0[1] = vfma((v2f)(g[u - 1]), S, b0[1]);
                    b1[1] = vfma((v2f)(g[u - 1]), P, b1[1]);
                }
            }
#pragma unroll
            for (int k = 0; k < 2; ++k) {
                *(v2f*)(wb + (4 + k) * REG_B) = b0[k];   // plane2 row k
                *(v2f*)(wb + (6 + k) * REG_B) = b1[k];   // plane3 row k
            }
        }
        __syncthreads();

        // ---- horizontal conv + SSIM, per output row k ----
#pragma unroll
        for (int k = 0; k < 2; ++k) {
            v2f h[4];
#pragma unroll
            for (int p = 0; p < 4; ++p) {
                const char* base = rb + (p * 2 + k) * REG_B;
                float hx = 0.0f, hy = 0.0f;
                // stream 7 x ds_read_b64: t = {s[2j], s[2j+1]}, s[n] = col c0-6+n
                // hx (col c0):   tap i uses s[i+1]; hy (col c0+1): s[i+2]
#pragma unroll
                for (int j = 0; j < 7; ++j) {
                    const v2f t = *(const v2f*)(base + j * 8);
                    const int ix0 = 2 * j - 1;   // hx tap for t.x
                    const int iy0 = 2 * j - 2;   // hy tap for t.x
                    if (ix0 >= 0 && ix0 <= 10) hx = fmaf(g[ix0], t.x, hx);
                    if (iy0 >= 0 && iy0 <= 10) hy = fmaf(g[iy0], t.x, hy);
                    const int ix1 = 2 * j;       // hx tap for t.y
                    const int iy1 = 2 * j - 1;   // hy tap for t.y
                    if (ix1 >= 0 && ix1 <= 10) hx = fmaf(g[ix1], t.y, hx);
                    if (iy1 >= 0 && iy1 <= 10) hy = fmaf(g[iy1], t.y, hy);
                }
                h[p] = (v2f){hx, hy};
            }
            const v2f mu1 = h[0], mu2 = h[1];
            const v2f mu1s = mu1 * mu1;
            const v2f mu2s = mu2 * mu2;
            const v2f mu12 = mu1 * mu2;
            const v2f sgs  = h[2] - mu1s - mu2s;       // sigma1^2 + sigma2^2
            const v2f sg12 = h[3] - mu12;
            const v2f num  = (2.f * mu12 + (v2f)(C1v)) * (2.f * sg12 + (v2f)(C2v));
            const v2f den  = (mu1s + mu2s + (v2f)(C1v)) * (sgs + (v2f)(C2v));
            v2f r = {__builtin_amdgcn_rcpf(den.x), __builtin_amdgcn_rcpf(den.y)};
            r = r * vfma(-den, r, (v2f)(2.0f));        // Newton -> ~1 ulp
            acc = fmaf(num.x, r.x, acc);
            acc = fmaf(num.y, r.y, acc);
        }
        if (step + 1 < CHUNK / 2) __syncthreads();     // before LDS overwrite
    }

    // block reduction -> single atomic per block (pre-scaled by 1/Npx)
#pragma unroll
    for (int off = 32; off > 0; off >>= 1)
        acc += __shfl_down(acc, off);
    if ((tid & 63) == 0) wred[tid >> 6] = acc;
    __syncthreads();
    if (tid == 0) {
        const float s = (wred[0] + wred[1]) + (wred[2] + wred[3]);
        atomicAdd(out, s * INV_NPX);
    }
}

extern "C" void kernel_launch(void* const* d_in, const int* in_sizes, int n_in,
                              void* d_out, int out_size, void* d_ws, size_t ws_size,
                              hipStream_t stream) {
    const float* img1   = (const float*)d_in[0];
    const float* img2   = (const float*)d_in[1];
    const float* window = (const float*)d_in[2];
    float* out = (float*)d_out;

    hipMemsetAsync(out, 0, sizeof(float), stream);   // graph-capturable
    dim3 grid(N_IMG, NCHUNK);
    ssim_partial_kernel<<<grid, 256, 0, stream>>>(img1, img2, window, out);
}

// Round 5
// 147.749 us; speedup vs baseline: 3.5858x; 1.3273x over previous
//
#include <hip/hip_runtime.h>

// SSIM (B=16, C=3, H=W=512, fp32) -> scalar mean.
// v12b: identical resubmission of v12 (round-4 hit GPU-acquisition timeout,
// no verdict). v11 structure with the spill fixed:
//  - __launch_bounds__(256,5): VGPR cap ~102 (v9's near-identical working set
//    measured 84) -> headroom, no spill. 5 blocks/CU = 20 waves/CU.
//  - Step loop NOT unrolled (#pragma unroll 1): prevents cross-step load
//    hoisting / liveness bloat that pushed v10/v11 over the cap. Ring shift
//    becomes ~20 v_movs/step -- cheap insurance.
//  - LDS layout (proven in v11: bank conflicts 1.58M -> 4.6K): 8 scalar
//    plane-row regions (4 planes x 2 rows), 528 dwords each, halo 6/6.
//    Reads/writes are lane-stride-2-dword = 2-way aliasing = free.
//  - g[] in SGPRs via readfirstlane; single atomicAdd per block.

typedef float v2f __attribute__((ext_vector_type(2)));

#define IMG_H 512
#define IMG_W 512
#define N_IMG 48                    // B*C
#define WS 11
#define PAD 5
#define CHUNK 16                    // output rows per block
#define NCHUNK (IMG_H / CHUNK)      // 32
#define RING 12                     // rows held in registers
#define REG_DW 528                  // dwords per plane-row region (524 used)
#define REG_B (REG_DW * 4)          // 2112 bytes
#define NREG 8                      // 4 planes x 2 rows
#define INV_NPX (1.0f / (48.0f * 512.0f * 512.0f))

__device__ __forceinline__ v2f vfma(v2f a, v2f b, v2f c) {
    return __builtin_elementwise_fma(a, b, c);
}
__device__ __forceinline__ float uni(float x) {   // force wave-uniform -> SGPR
    return __int_as_float(__builtin_amdgcn_readfirstlane(__float_as_int(x)));
}

__global__ __launch_bounds__(256, 5) void ssim_partial_kernel(
    const float* __restrict__ img1,
    const float* __restrict__ img2,
    const float* __restrict__ window,
    float* __restrict__ out)
{
    __shared__ __align__(16) char lds[NREG * REG_B];   // 16896 B
    __shared__ float wred[4];

    const int tid = threadIdx.x;
    const int bc  = blockIdx.x;              // image*channel 0..47
    const int r0  = blockIdx.y * CHUNK;
    const int c0  = tid * 2;                 // thread owns cols c0, c0+1

    // 1-D gaussian from window row 5 (w2d[5][j] = g5*g[j]); hoist to SGPRs.
    float g[WS];
    {
        const float g5  = sqrtf(window[5 * WS + 5]);
        const float inv = 1.0f / g5;
#pragma unroll
        for (int j = 0; j < WS; ++j) g[j] = uni(window[5 * WS + j] * inv);
    }
    const float C1v = 0.01f * 0.01f;
    const float C2v = 0.03f * 0.03f;

    const float* __restrict__ p1 = img1 + (size_t)bc * (IMG_H * IMG_W);
    const float* __restrict__ p2 = img2 + (size_t)bc * (IMG_H * IMG_W);

    // zero halo: dword idx 0..5 (cols -6..-1) and 518..523 (cols 512..517)
    if (tid < 96) {
        const int rg = tid / 12, h = tid % 12;
        const int idx = (h < 6) ? h : (512 + h);
        *(float*)(lds + rg * REG_B + idx * 4) = 0.0f;
    }
    __syncthreads();

    // LDS addressing: dword index of global col c is c+6 within a region.
    char*       wb = lds + (c0 + 6) * 4;     // write base (8B aligned)
    const char* rb = lds + c0 * 4;           // read base: col c0-6 (8B aligned)

    // register ring: slot i holds row R-5+i at step base R
    v2f rx1[RING], rx2[RING];
#pragma unroll
    for (int i = 0; i < RING; ++i) { rx1[i] = (v2f)(0.0f); rx2[i] = (v2f)(0.0f); }

    // warm-up: slots 2..11 <- rows r0-5 .. r0+4
#pragma unroll
    for (int i = 0; i < 10; ++i) {
        const int rr = r0 - PAD + i;
        v2f u1 = (v2f)(0.0f), u2 = (v2f)(0.0f);
        if (rr >= 0 && rr < IMG_H) {               // uniform branch
            u1 = *(const v2f*)(p1 + rr * IMG_W + c0);
            u2 = *(const v2f*)(p2 + rr * IMG_W + c0);
        }
        rx1[2 + i] = u1; rx2[2 + i] = u2;
    }

    float acc = 0.0f;

#pragma unroll 1
    for (int step = 0; step < CHUNK / 2; ++step) {
        const int R = r0 + step * 2;           // output rows R, R+1

        // shift ring by 2 (real v_movs; indices stay compile-time constant)
#pragma unroll
        for (int i = 0; i < RING - 2; ++i) { rx1[i] = rx1[i + 2]; rx2[i] = rx2[i + 2]; }
        // load rows R+5, R+6 -> slots 10, 11
#pragma unroll
        for (int j = 0; j < 2; ++j) {
            const int rr = R + PAD + j;
            v2f u1 = (v2f)(0.0f), u2 = (v2f)(0.0f);
            if (rr < IMG_H) {                  // uniform branch
                u1 = *(const v2f*)(p1 + rr * IMG_W + c0);
                u2 = *(const v2f*)(p2 + rr * IMG_W + c0);
            }
            rx1[10 + j] = u1; rx2[10 + j] = u2;
        }

        // ---- vertical pass A: mu1, mu2 (planes 0,1), rows k=0,1 ----
        {
            v2f a0[2] = {(v2f)(0.0f), (v2f)(0.0f)};
            v2f a1[2] = {(v2f)(0.0f), (v2f)(0.0f)};
#pragma unroll
            for (int k = 0; k < 2; ++k)
#pragma unroll
                for (int i = 0; i < WS; ++i) {
                    const v2f w = (v2f)(g[i]);
                    a0[k] = vfma(w, rx1[i + k], a0[k]);
                    a1[k] = vfma(w, rx2[i + k], a1[k]);
                }
#pragma unroll
            for (int k = 0; k < 2; ++k) {
                *(v2f*)(wb + (0 + k) * REG_B) = a0[k];   // plane0 row k
                *(v2f*)(wb + (2 + k) * REG_B) = a1[k];   // plane1 row k
            }
        }
        // ---- vertical pass B: S = x1^2+x2^2, P = x1*x2 (planes 2,3) ----
        {
            v2f b0[2] = {(v2f)(0.0f), (v2f)(0.0f)};
            v2f b1[2] = {(v2f)(0.0f), (v2f)(0.0f)};
#pragma unroll
            for (int u = 0; u < RING; ++u) {
                const v2f X1 = rx1[u], X2 = rx2[u];
                const v2f S = vfma(X1, X1, X2 * X2);
                const v2f P = X1 * X2;
                if (u <= 10) {                          // k=0 tap i=u
                    b0[0] = vfma((v2f)(g[u]), S, b0[0]);
                    b1[0] = vfma((v2f)(g[u]), P, b1[0]);
                }
                if (u >= 1) {                           // k=1 tap i=u-1
                    b0[1] = vfma((v2f)(g[u - 1]), S, b0[1]);
                    b1[1] = vfma((v2f)(g[u - 1]), P, b1[1]);
                }
            }
#pragma unroll
            for (int k = 0; k < 2; ++k) {
                *(v2f*)(wb + (4 + k) * REG_B) = b0[k];   // plane2 row k
                *(v2f*)(wb + (6 + k) * REG_B) = b1[k];   // plane3 row k
            }
        }
        __syncthreads();

        // ---- horizontal conv + SSIM, per output row k ----
#pragma unroll
        for (int k = 0; k < 2; ++k) {
            v2f h[4];
#pragma unroll
            for (int p = 0; p < 4; ++p) {
                const char* base = rb + (p * 2 + k) * REG_B;
                float hx = 0.0f, hy = 0.0f;
                // stream 7 x ds_read_b64: t = {s[2j], s[2j+1]}, s[n] = col c0-6+n
                // hx (col c0):   tap i uses s[i+1]; hy (col c0+1): s[i+2]
#pragma unroll
                for (int j = 0; j < 7; ++j) {
                    const v2f t = *(const v2f*)(base + j * 8);
                    const int ix0 = 2 * j - 1;   // hx tap for t.x
                    const int iy0 = 2 * j - 2;   // hy tap for t.x
                    if (ix0 >= 0 && ix0 <= 10) hx = fmaf(g[ix0], t.x, hx);
                    if (iy0 >= 0 && iy0 <= 10) hy = fmaf(g[iy0], t.x, hy);
                    const int ix1 = 2 * j;       // hx tap for t.y
                    const int iy1 = 2 * j - 1;   // hy tap for t.y
                    if (ix1 >= 0 && ix1 <= 10) hx = fmaf(g[ix1], t.y, hx);
                    if (iy1 >= 0 && iy1 <= 10) hy = fmaf(g[iy1], t.y, hy);
                }
                h[p] = (v2f){hx, hy};
            }
            const v2f mu1 = h[0], mu2 = h[1];
            const v2f mu1s = mu1 * mu1;
            const v2f mu2s = mu2 * mu2;
            const v2f mu12 = mu1 * mu2;
            const v2f sgs  = h[2] - mu1s - mu2s;       // sigma1^2 + sigma2^2
            const v2f sg12 = h[3] - mu12;
            const v2f num  = (2.f * mu12 + (v2f)(C1v)) * (2.f * sg12 + (v2f)(C2v));
            const v2f den  = (mu1s + mu2s + (v2f)(C1v)) * (sgs + (v2f)(C2v));
            v2f r = {__builtin_amdgcn_rcpf(den.x), __builtin_amdgcn_rcpf(den.y)};
            r = r * vfma(-den, r, (v2f)(2.0f));        // Newton -> ~1 ulp
            acc = fmaf(num.x, r.x, acc);
            acc = fmaf(num.y, r.y, acc);
        }
        __syncthreads();                               // before LDS overwrite
    }

    // block reduction -> single atomic per block (pre-scaled by 1/Npx)
#pragma unroll
    for (int off = 32; off > 0; off >>= 1)
        acc += __shfl_down(acc, off);
    if ((tid & 63) == 0) wred[tid >> 6] = acc;
    __syncthreads();
    if (tid == 0) {
        const float s = (wred[0] + wred[1]) + (wred[2] + wred[3]);
        atomicAdd(out, s * INV_NPX);
    }
}

extern "C" void kernel_launch(void* const* d_in, const int* in_sizes, int n_in,
                              void* d_out, int out_size, void* d_ws, size_t ws_size,
                              hipStream_t stream) {
    const float* img1   = (const float*)d_in[0];
    const float* img2   = (const float*)d_in[1];
    const float* window = (const float*)d_in[2];
    float* out = (float*)d_out;

    hipMemsetAsync(out, 0, sizeof(float), stream);   // graph-capturable
    dim3 grid(N_IMG, NCHUNK);
    ssim_partial_kernel<<<grid, 256, 0, stream>>>(img1, img2, window, out);
}